// Round 21
// baseline (84.715 us; speedup 1.0000x reference)
//
#include <hip/hip_runtime.h>
#include <stdint.h>

typedef __attribute__((ext_vector_type(4))) float f32x4;
typedef __attribute__((ext_vector_type(16))) float f32x16;
typedef __attribute__((ext_vector_type(8))) short bf16x8;
typedef __attribute__((ext_vector_type(4))) unsigned uint4v;
typedef unsigned long long ull;

#define GLB_AS const __attribute__((address_space(1)))
#define LDS_AS __attribute__((address_space(3)))

__device__ __forceinline__ short f2bf(float f) {
    union { float f; unsigned u; } x; x.f = f;
    unsigned r = x.u + 0x7FFFu + ((x.u >> 16) & 1u);
    return (short)(r >> 16);
}

// ---------------- fused pre: nodes->bf16 | W->W^T bf16 | adj bit-pack ----------------
__global__ void k_pre(const float* __restrict__ nodes, short* __restrict__ nodes_bf,
                      const float* __restrict__ Wq, const float* __restrict__ Wk,
                      const float* __restrict__ Wv, short* __restrict__ WT,
                      const int* __restrict__ adjs, unsigned* __restrict__ packed) {
    int bi = blockIdx.x, tid = threadIdx.x;
    if (bi < 2048) {
        int i = (bi * 256 + tid) * 8;
        float4 a = *(const float4*)(nodes + i);
        float4 b = *(const float4*)(nodes + i + 4);
        bf16x8 v;
        v[0] = f2bf(a.x); v[1] = f2bf(a.y); v[2] = f2bf(a.z); v[3] = f2bf(a.w);
        v[4] = f2bf(b.x); v[5] = f2bf(b.y); v[6] = f2bf(b.z); v[7] = f2bf(b.w);
        *(bf16x8*)(nodes_bf + i) = v;
    } else if (bi < 5120) {
        int g = (bi - 2048) * 256 + tid;
        int j = g >> 9, k = g & 511;
        int w = j >> 9, n = j & 511;
        const float* W = (w == 0) ? Wq : (w == 1) ? Wk : Wv;
        WT[g] = f2bf(W[k * 512 + n]);
    } else {
        int g = (bi - 5120) * 256 + tid;
        int wv = g >> 6, lane = g & 63;
        ull m = __ballot(adjs[(size_t)wv * 64 + lane] != 0);
        if (lane == 0) *(ull*)(packed + (size_t)wv * 2) = m;
    }
}

// ---------------- QKV = nodes_bf @ [Wq|Wk|Wv]  (M=8192,N=1536,K=512), 2-stage dbuf + XCD swizzle ----------------
// Q columns (0..511) pre-scaled by (1/sqrt(512))*log2(e) so attention can exp2 directly.
__global__ __launch_bounds__(256) void k_gemm_qkv(const short* __restrict__ A,
                                                  const short* __restrict__ WT,
                                                  short* __restrict__ C) {
    __shared__ short Asm[2][128 * 32];
    __shared__ short Bsm[2][128 * 32];
    const int tid = threadIdx.x;
    const int l = tid & 63, w = tid >> 6;
    const int wr = w >> 1, wc = w & 1;
    const int c16 = l & 15, g = l >> 4;
    const int wg = blockIdx.x;
    const int swz = (wg & 7) * 96 + (wg >> 3);   // 768 blocks, 8 XCDs, bijective
    const int row0 = (swz / 12) * 128, n0 = (swz % 12) * 128;
    f32x4 acc[4][4] = {};

    auto stage = [&](int kt, int bsel) {
        const int k0 = kt * 32;
#pragma unroll
        for (int i = 0; i < 2; ++i) {
            int ch = tid + 256 * i;
            int r = ch >> 2, gc = ch & 3;
            __builtin_amdgcn_global_load_lds((GLB_AS unsigned*)(A + (row0 + r) * 512 + k0 + 8 * gc),
                                             (LDS_AS unsigned*)(&Asm[bsel][ch * 8]), 16, 0, 0);
            __builtin_amdgcn_global_load_lds((GLB_AS unsigned*)(WT + (n0 + r) * 512 + k0 + 8 * gc),
                                             (LDS_AS unsigned*)(&Bsm[bsel][ch * 8]), 16, 0, 0);
        }
    };

    stage(0, 0);
    asm volatile("s_waitcnt vmcnt(0)" ::: "memory");
    __syncthreads();

    for (int kt = 0; kt < 16; ++kt) {
        const int cur = kt & 1;
        if (kt < 15) stage(kt + 1, cur ^ 1);
        bf16x8 af[4], bfr[4];
#pragma unroll
        for (int mf = 0; mf < 4; ++mf)
            af[mf] = *(const bf16x8*)&Asm[cur][(wr * 64 + mf * 16 + c16) * 32 + 8 * g];
#pragma unroll
        for (int nf = 0; nf < 4; ++nf)
            bfr[nf] = *(const bf16x8*)&Bsm[cur][(wc * 64 + nf * 16 + c16) * 32 + 8 * g];
#pragma unroll
        for (int mf = 0; mf < 4; ++mf)
#pragma unroll
            for (int nf = 0; nf < 4; ++nf)
                acc[mf][nf] = __builtin_amdgcn_mfma_f32_16x16x32_bf16(af[mf], bfr[nf], acc[mf][nf], 0, 0, 0);
        asm volatile("s_waitcnt vmcnt(0)" ::: "memory");
        __syncthreads();
    }
#pragma unroll
    for (int mf = 0; mf < 4; ++mf)
#pragma unroll
        for (int nf = 0; nf < 4; ++nf) {
            const float cs = (n0 + wc * 64 + nf * 16 < 512) ? 0.06375872022286384f : 1.0f;
#pragma unroll
            for (int r = 0; r < 4; ++r) {
                int row = row0 + wr * 64 + mf * 16 + 4 * g + r;
                int col = n0 + wc * 64 + nf * 16 + c16;
                C[row * 1536 + col] = f2bf(acc[mf][nf][r] * cs);
            }
        }
}

// ---------------- fused mid: Vt2 | Kt2 interleave | relations copy ----------------
// Vt2[b][h][n/8][d][n%8] = V ; Kt2[b][h][m/32][k/8][m%32][k%8] = K
__global__ __launch_bounds__(256) void k_mid(const short* __restrict__ QKV, short* __restrict__ Vt2,
                                             short* __restrict__ Kt2,
                                             const float* __restrict__ rel_in, float* __restrict__ rel_out) {
    const int bi = blockIdx.x, t = threadIdx.x;
    if (bi >= 1280) {
        // Kt2: one 16B chunk per thread. g over [b][m(1024)][c(64)]
        int g = (bi - 1280) * 256 + t;
        int c = g & 63, m = (g >> 6) & 1023, b = g >> 16;
        int h = c >> 4, khc = c & 15;
        bf16x8 v = *(const bf16x8*)(QKV + (size_t)(b * 1024 + m) * 1536 + 512 + c * 8);
        *(bf16x8*)(Kt2 + ((((size_t)(b * 4 + h) * 32 + (m >> 5)) * 16 + khc) * 32 + (m & 31)) * 8) = v;
        return;
    }
    if (bi >= 1024) {
        int i = ((bi - 1024) * 256 + t) * 4;
        *(float4*)(rel_out + i) = *(const float4*)(rel_in + i);
        return;
    }
    __shared__ short tile[64 * 65];
    const int b = bi >> 7, n0 = ((bi >> 3) & 15) * 64, d0 = (bi & 7) * 64;
#pragma unroll
    for (int i = 0; i < 16; ++i) {
        int idx = t + 256 * i;
        int nn = idx >> 6, dd = idx & 63;
        tile[nn * 65 + dd] = QKV[(b * 1024 + n0 + nn) * 1536 + 1024 + d0 + dd];
    }
    __syncthreads();
#pragma unroll
    for (int i = 0; i < 2; ++i) {
        int c = t + 256 * i;
        int dd = c >> 3, nl = (c & 7) * 8;
        int dg = d0 + dd;
        int h = dg >> 7, dh = dg & 127;
        bf16x8 v;
#pragma unroll
        for (int e = 0; e < 8; ++e)
            v[e] = tile[(nl + e) * 65 + dd];
        *(bf16x8*)(Vt2 + ((((size_t)(b * 4 + h)) * 128 + ((n0 + nl) >> 3)) * 128 + dh) * 8) = v;
    }
}

// ---------------- attention: 4 waves = 1 q-wave-group x 4 m-quarters, QBLK=32, KVBLK=32 ----------------
// Register-diet variant: no K prefetch regs (K loaded at tile start; latency hidden by 3 waves/SIMD),
// mask hoard 8 words. K/V direct-from-L2 via interleaved layouts; fixed-max softmax; LDS tree combine.
// grid 32x32 = 1024 blocks = 4 blocks/CU; target <=170 unified regs -> 3 waves/SIMD = 12 waves/CU.
__global__ __launch_bounds__(256, 2) void k_attn(const short* __restrict__ QKV, const short* __restrict__ Kt2,
                                                 const short* __restrict__ Vt2,
                                                 const unsigned* __restrict__ packed, float* __restrict__ out) {
    __shared__ char smem[33280];          // OshA[32x128]f32 @0 (16K), OshB @16K, lsh[4][32] @32K
    float* OshA = (float*)smem;
    float* OshB = (float*)(smem + 16384);
    float* lsh  = (float*)(smem + 32768);
    const int bh = blockIdx.x;            // 0..31
    const int b = bh >> 2, h = bh & 3;
    const int q0 = blockIdx.y * 32;
    const int tid = threadIdx.x, l = tid & 63;
    const int mg = tid >> 6;              // wave = m-quarter
    const int l31 = l & 31, hi = l >> 5;

    // Q fragments (B operand): lane = col q = q0 + l31, k-elems 16*kk + 8*hi .. +7
    bf16x8 aq[8];
    const short* Qb = QKV + (size_t)(b * 1024 + q0 + l31) * 1536 + h * 128;
#pragma unroll
    for (int kk = 0; kk < 8; ++kk)
        aq[kk] = *(const bf16x8*)(Qb + kk * 16 + hi * 8);

    f32x16 acc[4] = {};   // O: d-col = dd*32 + l31, q-row(in 32) = (reg&3)+8*(reg>>2)+4*hi
    float l_lane = 0.f;

    const short* K2b = Kt2 + (size_t)(b * 4 + h) * 131072;
    const short* V2b = Vt2 + (size_t)(b * 4 + h) * 131072;
    const unsigned* adjw = packed + (size_t)(b * 1024 + q0 + l31) * 32 + mg * 8;

    // hoist this wave's 8 mask words (one-time 32B read)
    unsigned mall[8];
#pragma unroll
    for (int i = 0; i < 2; ++i)
        *(uint4v*)(mall + 4 * i) = *(const uint4v*)(adjw + 4 * i);

#pragma unroll
    for (int t = 0; t < 8; ++t) {
        // K(t) loads first (QK consumes them soonest), then V(t)
        const int mt = mg * 8 + t;
        bf16x8 kcur[8], vcur[8];
#pragma unroll
        for (int kk = 0; kk < 8; ++kk)
            kcur[kk] = *(const bf16x8*)(K2b + ((size_t)(mt * 16 + 2 * kk + hi) * 32 + l31) * 8);
        const int mc0 = mg * 32 + t * 4;
#pragma unroll
        for (int ks = 0; ks < 2; ++ks)
#pragma unroll
            for (int dd = 0; dd < 4; ++dd)
                vcur[ks * 4 + dd] = *(const bf16x8*)(V2b + ((size_t)(mc0 + 2 * ks + hi) * 128 + dd * 32 + l31) * 8);

        // S^T = K Q^T : lane owns q = q0+l31, m(in 32) = (reg&3)+8*(reg>>2)+4*hi
        f32x16 s = (f32x16)0.f;
        __builtin_amdgcn_s_setprio(1);
#pragma unroll
        for (int kk = 0; kk < 8; ++kk)
            s = __builtin_amdgcn_mfma_f32_32x32x16_bf16(kcur[kk], aq[kk], s, 0, 0, 0);
        __builtin_amdgcn_s_setprio(0);

        // masked exp2, pack to bf16 pairs in-register; sum l
        unsigned pk[4][2];
        const unsigned mshift = mall[t] >> (4 * hi);
        float lt = 0.f;
#pragma unroll
        for (int j = 0; j < 4; ++j) {
            float p[4];
#pragma unroll
            for (int r = 0; r < 4; ++r) {
                float e = __builtin_amdgcn_exp2f(s[4 * j + r]);
                p[r] = ((mshift >> (8 * j + r)) & 1u) ? e : 0.f;
            }
            lt += (p[0] + p[1]) + (p[2] + p[3]);
            asm("v_cvt_pk_bf16_f32 %0, %1, %2" : "=v"(pk[j][0]) : "v"(p[0]), "v"(p[1]));
            asm("v_cvt_pk_bf16_f32 %0, %1, %2" : "=v"(pk[j][1]) : "v"(p[2]), "v"(p[3]));
        }
        l_lane += lt;

        // build PV A-fragments (shfl_xor(32) half-exchange, proven)
        union fragu { unsigned u[4]; bf16x8 v; };
        fragu frag[2];
#pragma unroll
        for (int kh = 0; kh < 2; ++kh) {
            unsigned a0 = pk[2 * kh][0], a1 = pk[2 * kh][1];
            unsigned b0 = pk[2 * kh + 1][0], b1 = pk[2 * kh + 1][1];
            unsigned rx0 = (unsigned)__shfl_xor((int)a0, 32);
            unsigned rx1 = (unsigned)__shfl_xor((int)a1, 32);
            unsigned rx2 = (unsigned)__shfl_xor((int)b0, 32);
            unsigned rx3 = (unsigned)__shfl_xor((int)b1, 32);
            fragu f;
            f.u[0] = hi ? rx2 : a0;
            f.u[1] = hi ? rx3 : a1;
            f.u[2] = hi ? b0 : rx0;
            f.u[3] = hi ? b1 : rx1;
            frag[kh] = f;
        }

        // PV: O += P @ V
        __builtin_amdgcn_s_setprio(1);
#pragma unroll
        for (int ks = 0; ks < 2; ++ks)
#pragma unroll
            for (int dd = 0; dd < 4; ++dd)
                acc[dd] = __builtin_amdgcn_mfma_f32_32x32x16_bf16(frag[ks].v, vcur[ks * 4 + dd], acc[dd], 0, 0, 0);
        __builtin_amdgcn_s_setprio(0);
    }

    // complete quarter-local l (lane and lane^32 hold complementary m-subsets of same q)
    l_lane += __shfl_xor(l_lane, 32);
    if (hi == 0) lsh[mg * 32 + l31] = l_lane;

    // tree combine across 4 m-quarters: mg1 -> OshA, mg3 -> OshB
    if (mg == 1 || mg == 3) {
        float* O = (mg == 1) ? OshA : OshB;
#pragma unroll
        for (int dd = 0; dd < 4; ++dd)
#pragma unroll
            for (int j = 0; j < 4; ++j)
#pragma unroll
                for (int r = 0; r < 4; ++r) {
                    int qrow = r + 8 * j + 4 * hi;
                    O[qrow * 128 + dd * 32 + l31] = acc[dd][4 * j + r];
                }
    }
    __syncthreads();
    if (mg == 0 || mg == 2) {
        const float* O = (mg == 0) ? OshA : OshB;
#pragma unroll
        for (int dd = 0; dd < 4; ++dd)
#pragma unroll
            for (int j = 0; j < 4; ++j)
#pragma unroll
                for (int r = 0; r < 4; ++r) {
                    int qrow = r + 8 * j + 4 * hi;
                    acc[dd][4 * j + r] += O[qrow * 128 + dd * 32 + l31];
                }
    }
    __syncthreads();
    if (mg == 2) {
#pragma unroll
        for (int dd = 0; dd < 4; ++dd)
#pragma unroll
            for (int j = 0; j < 4; ++j)
#pragma unroll
                for (int r = 0; r < 4; ++r) {
                    int qrow = r + 8 * j + 4 * hi;
                    OshA[qrow * 128 + dd * 32 + l31] = acc[dd][4 * j + r];
                }
    }
    __syncthreads();
    if (mg == 0) {
        float invq[16];
#pragma unroll
        for (int j = 0; j < 4; ++j)
#pragma unroll
            for (int r = 0; r < 4; ++r) {
                int qrow = r + 8 * j + 4 * hi;
                invq[4 * j + r] = 1.f / (lsh[qrow] + lsh[32 + qrow] + lsh[64 + qrow] + lsh[96 + qrow]);
            }
#pragma unroll
        for (int dd = 0; dd < 4; ++dd)
#pragma unroll
            for (int j = 0; j < 4; ++j)
#pragma unroll
                for (int r = 0; r < 4; ++r) {
                    int qrow = r + 8 * j + 4 * hi;
                    float o = (acc[dd][4 * j + r] + OshA[qrow * 128 + dd * 32 + l31]) * invq[4 * j + r];
                    out[(size_t)(b * 1024 + q0 + qrow) * 512 + h * 128 + dd * 32 + l31] = fmaxf(o, 0.f);
                }
    }
}

extern "C" void kernel_launch(void* const* d_in, const int* in_sizes, int n_in,
                              void* d_out, int out_size, void* d_ws, size_t ws_size,
                              hipStream_t stream) {
    const int*   adjs      = (const int*)d_in[0];
    const float* nodes     = (const float*)d_in[2];
    const float* relations = (const float*)d_in[4];
    const float* Wq        = (const float*)d_in[5];
    const float* Wk        = (const float*)d_in[6];
    const float* Wv        = (const float*)d_in[7];

    char* ws = (char*)d_ws;
    short* nodes_bf   = (short*)(ws);                // 8,388,608 B
    short* WT         = (short*)(ws + 8388608);      // 1,572,864 B
    short* QKV        = (short*)(ws + 9961472);      // 25,165,824 B  [8192][1536]
    short* Vt2        = (short*)(ws + 35127296);     // 8,388,608 B   [8][4][128][128][8]
    unsigned* adjpack = (unsigned*)(ws + 43515904);  // 1,048,576 B   [8][1024][32]
    short* Kt2        = (short*)(ws + 44564480);     // 8,388,608 B   [8][4][32][16][32][8]

    float* out     = (float*)d_out;
    float* out_rel = out + 4194304;

    k_pre<<<dim3(37888), dim3(256), 0, stream>>>(nodes, nodes_bf, Wq, Wk, Wv, WT, adjs, adjpack);
    k_gemm_qkv<<<dim3(768), dim3(256), 0, stream>>>(nodes_bf, WT, QKV);
    k_mid<<<dim3(3328), dim3(256), 0, stream>>>(QKV, Vt2, Kt2, relations, out_rel);
    k_attn<<<dim3(32, 32), dim3(256), 0, stream>>>(QKV, Kt2, Vt2, adjpack, out);
}

// Round 22
// 79.336 us; speedup vs baseline: 1.0678x; 1.0678x over previous
//
#include <hip/hip_runtime.h>
#include <stdint.h>

typedef __attribute__((ext_vector_type(4))) float f32x4;
typedef __attribute__((ext_vector_type(16))) float f32x16;
typedef __attribute__((ext_vector_type(8))) short bf16x8;
typedef __attribute__((ext_vector_type(4))) unsigned uint4v;
typedef unsigned long long ull;

#define GLB_AS const __attribute__((address_space(1)))
#define LDS_AS __attribute__((address_space(3)))

__device__ __forceinline__ short f2bf(float f) {
    union { float f; unsigned u; } x; x.f = f;
    unsigned r = x.u + 0x7FFFu + ((x.u >> 16) & 1u);
    return (short)(r >> 16);
}

// ---------------- fused pre: nodes->bf16 | W->W^T bf16 | adj bit-pack ----------------
__global__ void k_pre(const float* __restrict__ nodes, short* __restrict__ nodes_bf,
                      const float* __restrict__ Wq, const float* __restrict__ Wk,
                      const float* __restrict__ Wv, short* __restrict__ WT,
                      const int* __restrict__ adjs, unsigned* __restrict__ packed) {
    int bi = blockIdx.x, tid = threadIdx.x;
    if (bi < 2048) {
        int i = (bi * 256 + tid) * 8;
        float4 a = *(const float4*)(nodes + i);
        float4 b = *(const float4*)(nodes + i + 4);
        bf16x8 v;
        v[0] = f2bf(a.x); v[1] = f2bf(a.y); v[2] = f2bf(a.z); v[3] = f2bf(a.w);
        v[4] = f2bf(b.x); v[5] = f2bf(b.y); v[6] = f2bf(b.z); v[7] = f2bf(b.w);
        *(bf16x8*)(nodes_bf + i) = v;
    } else if (bi < 5120) {
        int g = (bi - 2048) * 256 + tid;
        int j = g >> 9, k = g & 511;
        int w = j >> 9, n = j & 511;
        const float* W = (w == 0) ? Wq : (w == 1) ? Wk : Wv;
        WT[g] = f2bf(W[k * 512 + n]);
    } else {
        int g = (bi - 5120) * 256 + tid;
        int wv = g >> 6, lane = g & 63;
        ull m = __ballot(adjs[(size_t)wv * 64 + lane] != 0);
        if (lane == 0) *(ull*)(packed + (size_t)wv * 2) = m;
    }
}

// ---------------- QKV = nodes_bf @ [Wq|Wk|Wv]  (M=8192,N=1536,K=512), 2-stage dbuf + XCD swizzle ----------------
// Q columns (0..511) pre-scaled by (1/sqrt(512))*log2(e) so attention can exp2 directly.
__global__ __launch_bounds__(256) void k_gemm_qkv(const short* __restrict__ A,
                                                  const short* __restrict__ WT,
                                                  short* __restrict__ C) {
    __shared__ short Asm[2][128 * 32];
    __shared__ short Bsm[2][128 * 32];
    const int tid = threadIdx.x;
    const int l = tid & 63, w = tid >> 6;
    const int wr = w >> 1, wc = w & 1;
    const int c16 = l & 15, g = l >> 4;
    const int wg = blockIdx.x;
    const int swz = (wg & 7) * 96 + (wg >> 3);   // 768 blocks, 8 XCDs, bijective
    const int row0 = (swz / 12) * 128, n0 = (swz % 12) * 128;
    f32x4 acc[4][4] = {};

    auto stage = [&](int kt, int bsel) {
        const int k0 = kt * 32;
#pragma unroll
        for (int i = 0; i < 2; ++i) {
            int ch = tid + 256 * i;
            int r = ch >> 2, gc = ch & 3;
            __builtin_amdgcn_global_load_lds((GLB_AS unsigned*)(A + (row0 + r) * 512 + k0 + 8 * gc),
                                             (LDS_AS unsigned*)(&Asm[bsel][ch * 8]), 16, 0, 0);
            __builtin_amdgcn_global_load_lds((GLB_AS unsigned*)(WT + (n0 + r) * 512 + k0 + 8 * gc),
                                             (LDS_AS unsigned*)(&Bsm[bsel][ch * 8]), 16, 0, 0);
        }
    };

    stage(0, 0);
    asm volatile("s_waitcnt vmcnt(0)" ::: "memory");
    __syncthreads();

    for (int kt = 0; kt < 16; ++kt) {
        const int cur = kt & 1;
        if (kt < 15) stage(kt + 1, cur ^ 1);
        bf16x8 af[4], bfr[4];
#pragma unroll
        for (int mf = 0; mf < 4; ++mf)
            af[mf] = *(const bf16x8*)&Asm[cur][(wr * 64 + mf * 16 + c16) * 32 + 8 * g];
#pragma unroll
        for (int nf = 0; nf < 4; ++nf)
            bfr[nf] = *(const bf16x8*)&Bsm[cur][(wc * 64 + nf * 16 + c16) * 32 + 8 * g];
#pragma unroll
        for (int mf = 0; mf < 4; ++mf)
#pragma unroll
            for (int nf = 0; nf < 4; ++nf)
                acc[mf][nf] = __builtin_amdgcn_mfma_f32_16x16x32_bf16(af[mf], bfr[nf], acc[mf][nf], 0, 0, 0);
        asm volatile("s_waitcnt vmcnt(0)" ::: "memory");
        __syncthreads();
    }
#pragma unroll
    for (int mf = 0; mf < 4; ++mf)
#pragma unroll
        for (int nf = 0; nf < 4; ++nf) {
            const float cs = (n0 + wc * 64 + nf * 16 < 512) ? 0.06375872022286384f : 1.0f;
#pragma unroll
            for (int r = 0; r < 4; ++r) {
                int row = row0 + wr * 64 + mf * 16 + 4 * g + r;
                int col = n0 + wc * 64 + nf * 16 + c16;
                C[row * 1536 + col] = f2bf(acc[mf][nf][r] * cs);
            }
        }
}

// ---------------- fused mid: Vt2 | Kt2 interleave | relations copy ----------------
// Vt2[b][h][n/8][d][n%8] = V ; Kt2[b][h][m/32][k/8][m%32][k%8] = K
__global__ __launch_bounds__(256) void k_mid(const short* __restrict__ QKV, short* __restrict__ Vt2,
                                             short* __restrict__ Kt2,
                                             const float* __restrict__ rel_in, float* __restrict__ rel_out) {
    const int bi = blockIdx.x, t = threadIdx.x;
    if (bi >= 1280) {
        // Kt2: one 16B chunk per thread. g over [b][m(1024)][c(64)]
        int g = (bi - 1280) * 256 + t;
        int c = g & 63, m = (g >> 6) & 1023, b = g >> 16;
        int h = c >> 4, khc = c & 15;
        bf16x8 v = *(const bf16x8*)(QKV + (size_t)(b * 1024 + m) * 1536 + 512 + c * 8);
        *(bf16x8*)(Kt2 + ((((size_t)(b * 4 + h) * 32 + (m >> 5)) * 16 + khc) * 32 + (m & 31)) * 8) = v;
        return;
    }
    if (bi >= 1024) {
        int i = ((bi - 1024) * 256 + t) * 4;
        *(float4*)(rel_out + i) = *(const float4*)(rel_in + i);
        return;
    }
    __shared__ short tile[64 * 65];
    const int b = bi >> 7, n0 = ((bi >> 3) & 15) * 64, d0 = (bi & 7) * 64;
#pragma unroll
    for (int i = 0; i < 16; ++i) {
        int idx = t + 256 * i;
        int nn = idx >> 6, dd = idx & 63;
        tile[nn * 65 + dd] = QKV[(b * 1024 + n0 + nn) * 1536 + 1024 + d0 + dd];
    }
    __syncthreads();
#pragma unroll
    for (int i = 0; i < 2; ++i) {
        int c = t + 256 * i;
        int dd = c >> 3, nl = (c & 7) * 8;
        int dg = d0 + dd;
        int h = dg >> 7, dh = dg & 127;
        bf16x8 v;
#pragma unroll
        for (int e = 0; e < 8; ++e)
            v[e] = tile[(nl + e) * 65 + dd];
        *(bf16x8*)(Vt2 + ((((size_t)(b * 4 + h)) * 128 + ((n0 + nl) >> 3)) * 128 + dh) * 8) = v;
    }
}

// ---------------- attention: 8 waves = 4 q-waves x 2 m-groups, KVBLK=32, NO LDS/barriers in loop ----------------
// K and V direct-from-L2 via interleaved layouts; fixed-max softmax (Q pre-scaled); in-LDS combine epilogue.
// All 16 per-lane mask words hoisted to registers (removes 15 uncoalesced in-loop gathers).
__global__ __launch_bounds__(512, 2) void k_attn(const short* __restrict__ QKV, const short* __restrict__ Kt2,
                                                 const short* __restrict__ Vt2,
                                                 const unsigned* __restrict__ packed, float* __restrict__ out) {
    __shared__ char smem[66560];          // epilogue only: [0,64K) 128x128 f32 Osh; [64K,+1K) lsh[2][128]
    float* Osh = (float*)smem;
    float* lsh = (float*)(smem + 65536);
    const int bh = blockIdx.x;            // 0..31
    const int b = bh >> 2, h = bh & 3;
    const int q0 = blockIdx.y * 128;
    const int tid = threadIdx.x, l = tid & 63, wid = tid >> 6;
    const int mg = wid >> 2, wq = wid & 3;
    const int l31 = l & 31, hi = l >> 5;
    const int qw = q0 + wq * 32;

    // Q fragments (B operand): lane = col q = qw + l31, k-elems 16*kk + 8*hi .. +7
    bf16x8 aq[8];
    const short* Qb = QKV + (size_t)(b * 1024 + qw + l31) * 1536 + h * 128;
#pragma unroll
    for (int kk = 0; kk < 8; ++kk)
        aq[kk] = *(const bf16x8*)(Qb + kk * 16 + hi * 8);

    f32x16 acc[4] = {};   // O: d-col = dd*32 + l31, q-row(in 32) = (reg&3)+8*(reg>>2)+4*hi
    float l_lane = 0.f;

    const short* K2b = Kt2 + (size_t)(b * 4 + h) * 131072;
    const short* V2b = Vt2 + (size_t)(b * 4 + h) * 131072;
    const unsigned* adjw = packed + (size_t)(b * 1024 + qw + l31) * 32 + mg * 16;

    // hoist all 16 mask words for this lane (one-time 64B read, 4x dwordx4)
    unsigned mall[16];
#pragma unroll
    for (int i = 0; i < 4; ++i)
        *(uint4v*)(mall + 4 * i) = *(const uint4v*)(adjw + 4 * i);

    bf16x8 kcur[8], knxt[8], vcur[8];
    // prologue: K(0)
    {
        const int mt = mg * 16;
#pragma unroll
        for (int kk = 0; kk < 8; ++kk)
            kcur[kk] = *(const bf16x8*)(K2b + ((size_t)(mt * 16 + 2 * kk + hi) * 32 + l31) * 8);
    }

#pragma unroll
    for (int t = 0; t < 16; ++t) {
        // V(t) issued first: consumed after QK+softmax (~500cy later)
        const int mc0 = mg * 64 + t * 4;
#pragma unroll
        for (int ks = 0; ks < 2; ++ks)
#pragma unroll
            for (int dd = 0; dd < 4; ++dd)
                vcur[ks * 4 + dd] = *(const bf16x8*)(V2b + ((size_t)(mc0 + 2 * ks + hi) * 128 + dd * 32 + l31) * 8);
        // K(t+1) prefetch
        if (t < 15) {
            const int mt = mg * 16 + t + 1;
#pragma unroll
            for (int kk = 0; kk < 8; ++kk)
                knxt[kk] = *(const bf16x8*)(K2b + ((size_t)(mt * 16 + 2 * kk + hi) * 32 + l31) * 8);
        }

        // S^T = K Q^T : lane owns q = qw+l31, m(in 32) = (reg&3)+8*(reg>>2)+4*hi
        f32x16 s = (f32x16)0.f;
        __builtin_amdgcn_s_setprio(1);
#pragma unroll
        for (int kk = 0; kk < 8; ++kk)
            s = __builtin_amdgcn_mfma_f32_32x32x16_bf16(kcur[kk], aq[kk], s, 0, 0, 0);
        __builtin_amdgcn_s_setprio(0);

        // masked exp2, pack to bf16 pairs in-register; sum l
        unsigned pk[4][2];
        const unsigned mshift = mall[t] >> (4 * hi);
        float lt = 0.f;
#pragma unroll
        for (int j = 0; j < 4; ++j) {
            float p[4];
#pragma unroll
            for (int r = 0; r < 4; ++r) {
                float e = __builtin_amdgcn_exp2f(s[4 * j + r]);
                p[r] = ((mshift >> (8 * j + r)) & 1u) ? e : 0.f;
            }
            lt += (p[0] + p[1]) + (p[2] + p[3]);
            asm("v_cvt_pk_bf16_f32 %0, %1, %2" : "=v"(pk[j][0]) : "v"(p[0]), "v"(p[1]));
            asm("v_cvt_pk_bf16_f32 %0, %1, %2" : "=v"(pk[j][1]) : "v"(p[2]), "v"(p[3]));
        }
        l_lane += lt;

        // build PV A-fragments (shfl_xor(32) half-exchange, proven)
        union fragu { unsigned u[4]; bf16x8 v; };
        fragu frag[2];
#pragma unroll
        for (int kh = 0; kh < 2; ++kh) {
            unsigned a0 = pk[2 * kh][0], a1 = pk[2 * kh][1];
            unsigned b0 = pk[2 * kh + 1][0], b1 = pk[2 * kh + 1][1];
            unsigned rx0 = (unsigned)__shfl_xor((int)a0, 32);
            unsigned rx1 = (unsigned)__shfl_xor((int)a1, 32);
            unsigned rx2 = (unsigned)__shfl_xor((int)b0, 32);
            unsigned rx3 = (unsigned)__shfl_xor((int)b1, 32);
            fragu f;
            f.u[0] = hi ? rx2 : a0;
            f.u[1] = hi ? rx3 : a1;
            f.u[2] = hi ? b0 : rx0;
            f.u[3] = hi ? b1 : rx1;
            frag[kh] = f;
        }

        // PV: O += P @ V
        __builtin_amdgcn_s_setprio(1);
#pragma unroll
        for (int ks = 0; ks < 2; ++ks)
#pragma unroll
            for (int dd = 0; dd < 4; ++dd)
                acc[dd] = __builtin_amdgcn_mfma_f32_32x32x16_bf16(frag[ks].v, vcur[ks * 4 + dd], acc[dd], 0, 0, 0);
        __builtin_amdgcn_s_setprio(0);

        // rotate
#pragma unroll
        for (int kk = 0; kk < 8; ++kk) kcur[kk] = knxt[kk];
    }

    // complete group-local l (lane and lane^32 hold complementary m-subsets of same q)
    l_lane += __shfl_xor(l_lane, 32);
    if (hi == 0) lsh[mg * 128 + wq * 32 + l31] = l_lane;

    if (mg == 1) {
#pragma unroll
        for (int dd = 0; dd < 4; ++dd)
#pragma unroll
            for (int j = 0; j < 4; ++j)
#pragma unroll
                for (int r = 0; r < 4; ++r) {
                    int qrow = wq * 32 + r + 8 * j + 4 * hi;
                    Osh[qrow * 128 + dd * 32 + l31] = acc[dd][4 * j + r];
                }
    }
    __syncthreads();
    if (mg == 0) {
        float invq[16];
#pragma unroll
        for (int j = 0; j < 4; ++j)
#pragma unroll
            for (int r = 0; r < 4; ++r) {
                int qrow = wq * 32 + r + 8 * j + 4 * hi;
                invq[4 * j + r] = 1.f / (lsh[qrow] + lsh[128 + qrow]);
            }
#pragma unroll
        for (int dd = 0; dd < 4; ++dd)
#pragma unroll
            for (int j = 0; j < 4; ++j)
#pragma unroll
                for (int r = 0; r < 4; ++r) {
                    int qrow = wq * 32 + r + 8 * j + 4 * hi;
                    float o = (acc[dd][4 * j + r] + Osh[qrow * 128 + dd * 32 + l31]) * invq[4 * j + r];
                    out[(size_t)(b * 1024 + q0 + qrow) * 512 + h * 128 + dd * 32 + l31] = fmaxf(o, 0.f);
                }
    }
}

extern "C" void kernel_launch(void* const* d_in, const int* in_sizes, int n_in,
                              void* d_out, int out_size, void* d_ws, size_t ws_size,
                              hipStream_t stream) {
    const int*   adjs      = (const int*)d_in[0];
    const float* nodes     = (const float*)d_in[2];
    const float* relations = (const float*)d_in[4];
    const float* Wq        = (const float*)d_in[5];
    const float* Wk        = (const float*)d_in[6];
    const float* Wv        = (const float*)d_in[7];

    char* ws = (char*)d_ws;
    short* nodes_bf   = (short*)(ws);                // 8,388,608 B
    short* WT         = (short*)(ws + 8388608);      // 1,572,864 B
    short* QKV        = (short*)(ws + 9961472);      // 25,165,824 B  [8192][1536]
    short* Vt2        = (short*)(ws + 35127296);     // 8,388,608 B   [8][4][128][128][8]
    unsigned* adjpack = (unsigned*)(ws + 43515904);  // 1,048,576 B   [8][1024][32]
    short* Kt2        = (short*)(ws + 44564480);     // 8,388,608 B   [8][4][32][16][32][8]

    float* out     = (float*)d_out;
    float* out_rel = out + 4194304;

    k_pre<<<dim3(37888), dim3(256), 0, stream>>>(nodes, nodes_bf, Wq, Wk, Wv, WT, adjs, adjpack);
    k_gemm_qkv<<<dim3(768), dim3(256), 0, stream>>>(nodes_bf, WT, QKV);
    k_mid<<<dim3(3328), dim3(256), 0, stream>>>(QKV, Vt2, Kt2, relations, out_rel);
    k_attn<<<dim3(32, 8), dim3(512), 0, stream>>>(QKV, Kt2, Vt2, adjpack, out);
}